// Round 6
// baseline (392.789 us; speedup 1.0000x reference)
//
#include <hip/hip_runtime.h>

// VQBlock: x[16,64,64,256] fp32, dict[256,1024] fp32.
// out = concat(q_st flat [16777216], loss [1]) fp32.
//
// Round 8 = r7 geometry (M=16/wave, RPB=64, proven select/rescan/epilogue)
// with the B-path read DIRECTLY from L2-resident packB -- no LDS staging, no
// __syncthreads in the chunk loop.
//  - r7 lesson: killing bank conflicts + VALU (both landed per counters) moved
//    time 0. Critical path = exposed load latency + vmcnt(0) barrier drains.
//  - r6 lesson: its 3.8ms was register SPILL (VGPR=128 cap + 38MB phantom
//    writes), NOT direct-global B reads. This round bounds live registers:
//    M=16 (afrag 32) + explicit 2-slice b pipeline (32) + acc 16 + sel 8
//    ~= 110 < 128 cap at __launch_bounds__(256,4). Spill tripwire: WRITE_SIZE.
//  - packB layout (unchanged from r7): fragment (cc,kk,t) is contiguous
//    lane-linear 1KB at packB + cc*32KB + (kk*4+t)*1KB + lane*16B.
//  - Raw s_barrier once per chunk (pacing only; no memory dep -> no drain):
//    keeps the block's 4 waves near-lockstep on the same 32KB chunk (L1 reuse).
//  - Packed-u32 branchless top-2 (absmax 0.0 in r5/r6/r7): EPS_TIE 6e-3,
//    dictnorm +8 bias; ambiguous rows -> unchanged np-fp32-faithful rescan.
//  - q_st written as fl(x + fl(q-x)) to match np exactly.

#define NROWS   65536
#define DIM     256
#define NCODE   1024
#define RPB     64                  // rows per block = 4 waves x 16 rows
#define NBLK    (NROWS / RPB)       // 1024
#define EPS_TIE 6e-3f

typedef _Float16 half8 __attribute__((ext_vector_type(8)));
typedef float    f32x4 __attribute__((ext_vector_type(4)));

// ---------- merged prep kernel ----------
// transpose + permuted f16 MFMA-B pack + (blocks 0-3) dictnorm (+8 bias).
// packB element e: j = e&7, o = (e>>3)&2047, cc = e>>14;
//   l15 = o&15, q = (o>>4)&3, t = (o>>6)&3, kk = o>>8;
//   value = f16(dict[kk*32+q*8+j][cc*64+t*16+l15])
__global__ void k_prep(const float* __restrict__ dict, float* __restrict__ dictT,
                       float* __restrict__ dictnorm, unsigned short* __restrict__ packB) {
    int gid = blockIdx.x * 256 + threadIdx.x;          // grid 256 x 256
#pragma unroll
    for (int ii = 0; ii < 4; ++ii) {
        int e = ii * 65536 + gid;
        // transpose (coalesced read)
        { int d = e >> 10, k = e & 1023; dictT[k * DIM + d] = dict[e]; }
        // permuted pack (coalesced write)
        { int j = e & 7, o = (e >> 3) & 2047, cc = e >> 14;
          int l15 = o & 15, q = (o >> 4) & 3, t = (o >> 6) & 3, kk = o >> 8;
          int d = kk * 32 + q * 8 + j;
          int n = cc * 64 + t * 16 + l15;
          _Float16 h = (_Float16)dict[d * NCODE + n];   // RTN cvt
          packB[e] = *(unsigned short*)&h; }
    }
    if (blockIdx.x < 4) {
        int k = blockIdx.x * 256 + threadIdx.x;
        float s = 0.f;
#pragma unroll 8
        for (int d = 0; d < DIM; ++d) {
            float v = dict[d * NCODE + k];
            s = fmaf(v, v, s);
        }
        dictnorm[k] = s + 8.0f;    // bias for packed-selection positivity; cancels in gaps
    }
}

// np pairwise sum of squares of 128 contiguous elements
__device__ __forceinline__ float np_pairwise_sq_128(const float* a, int stride) {
    float r[8];
#pragma unroll
    for (int j = 0; j < 8; ++j) {
        float v = a[j * stride];
        r[j] = __fmul_rn(v, v);
    }
    for (int i = 8; i < 128; i += 8) {
#pragma unroll
        for (int j = 0; j < 8; ++j) {
            float v = a[(i + j) * stride];
            r[j] = __fadd_rn(r[j], __fmul_rn(v, v));
        }
    }
    return __fadd_rn(__fadd_rn(__fadd_rn(r[0], r[1]), __fadd_rn(r[2], r[3])),
                     __fadd_rn(__fadd_rn(r[4], r[5]), __fadd_rn(r[6], r[7])));
}

// ---------- main kernel (no LDS staging, no __syncthreads in hot loop) ----------

__global__ __launch_bounds__(256, 4) void k_vq(
    const float* __restrict__ x, const float* __restrict__ dict,
    const float* __restrict__ dictT, const float* __restrict__ dictnorm,
    const unsigned short* __restrict__ packB,
    float* __restrict__ out, double* __restrict__ block_sums)
{
    __shared__ float row_gap[RPB];
    __shared__ int   row_k1[RPB];
    __shared__ float red_d[256];
    __shared__ int   red_k[256];
    __shared__ float wred[4];
    __shared__ int   amb_list[RPB];
    __shared__ int   amb_cnt;

    const int tid  = threadIdx.x;
    const int ln   = tid & 63, wv = tid >> 6;
    const int l15  = ln & 15, q = ln >> 4;
    const int row0 = blockIdx.x * RPB;

    if (tid == 0) amb_cnt = 0;

    // A fragments (register-resident, reused over all 16 chunks):
    // lane provides A row m=l15 (x row row0 + wv*16 + l15), k = kk*32 + q*8 + j
    half8 afrag[8];
    {
        const float* ar = x + (size_t)(row0 + wv * 16 + l15) * DIM + q * 8;
#pragma unroll
        for (int kk = 0; kk < 8; ++kk) {
            const float4 p0 = *(const float4*)(ar + kk * 32);
            const float4 p1 = *(const float4*)(ar + kk * 32 + 4);
            half8 h;
            h[0] = (_Float16)p0.x; h[1] = (_Float16)p0.y; h[2] = (_Float16)p0.z; h[3] = (_Float16)p0.w;
            h[4] = (_Float16)p1.x; h[5] = (_Float16)p1.y; h[6] = (_Float16)p1.z; h[7] = (_Float16)p1.w;
            afrag[kk] = h;
        }
    }

    // packed top-2 per lane for its 4 C-rows (local rows q*4+i)
    unsigned p1v[4], p2v[4];
#pragma unroll
    for (int i = 0; i < 4; ++i) { p1v[i] = 0xFFFFFFFFu; p2v[i] = 0xFFFFFFFFu; }

    // per-lane B base: fragment (cc,kk,t) lives at shorts
    //   cc*16384 + (kk*4+t)*512 + (q*128 + l15*8)   [lane-linear 1KB per fragment]
    const unsigned short* bl = packB + q * 128 + l15 * 8;

    // 2-slice register pipeline: b0/b1 alternate as cur/next (static via kk&1)
    half8 b0[4], b1[4];
#pragma unroll
    for (int t = 0; t < 4; ++t) b0[t] = *(const half8*)(bl + t * 512);   // cc=0,kk=0

    for (int cc = 0; cc < 16; ++cc) {
        const int c0 = cc * 64;
        const unsigned short* bc = bl + (size_t)cc * 16384;

        float dn[4];
#pragma unroll
        for (int t = 0; t < 4; ++t) dn[t] = dictnorm[c0 + t * 16 + l15];   // ||d||^2 + 8

        const f32x4 zero = {0.f, 0.f, 0.f, 0.f};
        f32x4 acc[4];
#pragma unroll
        for (int t = 0; t < 4; ++t) acc[t] = zero;

#pragma unroll
        for (int kk = 0; kk < 8; ++kk) {
            if (kk < 7) {
                // load next k-slice into the free buffer
#pragma unroll
                for (int t = 0; t < 4; ++t) {
                    const half8 v = *(const half8*)(bc + ((kk + 1) * 4 + t) * 512);
                    if (kk & 1) b0[t] = v; else b1[t] = v;
                }
            } else if (cc < 15) {
                // kk=7 uses b1; prefetch next chunk's slice 0 into b0
#pragma unroll
                for (int t = 0; t < 4; ++t) b0[t] = *(const half8*)(bc + 16384 + t * 512);
            }
#pragma unroll
            for (int t = 0; t < 4; ++t) {              // 4 independent MFMA chains
                const half8 bb = (kk & 1) ? b1[t] : b0[t];
                acc[t] = __builtin_amdgcn_mfma_f32_16x16x32_f16(afrag[kk], bb, acc[t], 0, 0, 0);
            }
        }

        // packed top-2 update: branchless, index-ascending tiebreak
#pragma unroll
        for (int t = 0; t < 4; ++t) {
            const unsigned kbase = (unsigned)(c0 + t * 16 + l15);
#pragma unroll
            for (int i = 0; i < 4; ++i) {
                const float s = fmaf(-2.f, acc[t][i], dn[t]);      // in (1.8, 14.6)
                const unsigned pk = (__float_as_uint(s) & 0xFFFFFC00u) | kbase;
                const unsigned mx = p1v[i] > pk ? p1v[i] : pk;
                p2v[i] = p2v[i] < mx ? p2v[i] : mx;
                p1v[i] = p1v[i] < pk ? p1v[i] : pk;
            }
        }
        __builtin_amdgcn_s_barrier();   // pacing only: keep 4 waves lockstep for L1 reuse
    }

    // top-2 merge across the 16 lanes sharing quad q (they hold the same 4 rows)
#pragma unroll
    for (int i = 0; i < 4; ++i) {
        unsigned a1 = p1v[i], a2 = p2v[i];
#pragma unroll
        for (int m = 1; m < 16; m <<= 1) {
            const unsigned o1 = __shfl_xor(a1, m);
            const unsigned o2 = __shfl_xor(a2, m);
            const unsigned mx = a1 > o1 ? a1 : o1;
            a1 = a1 < o1 ? a1 : o1;
            const unsigned mn2 = a2 < o2 ? a2 : o2;
            a2 = mx < mn2 ? mx : mn2;
        }
        if (l15 == 0) {
            const int r = wv * 16 + q * 4 + i;
            row_k1[r]  = (int)(a1 & 1023u);
            row_gap[r] = __uint_as_float(a2 & 0xFFFFFC00u) - __uint_as_float(a1 & 0xFFFFFC00u);
        }
    }
    __syncthreads();

    if (tid < RPB && row_gap[tid] < EPS_TIE) {
        int p = atomicAdd(&amb_cnt, 1);
        amb_list[p] = tid;
    }
    __syncthreads();
    const int namb = amb_cnt;

    // np-fp32-faithful full rescan of ambiguous rows (proven; unchanged)
    for (int a = 0; a < namb; ++a) {
        const int r = amb_list[a];
        const float* xr = x + (size_t)(row0 + r) * DIM;
        const float nf = __fadd_rn(np_pairwise_sq_128(xr, 1), np_pairwise_sq_128(xr + 128, 1));
        float bd = 3.4e38f; int bk = 0x7fffffff;
#pragma unroll
        for (int i = 0; i < 4; ++i) {
            const int k = i * 256 + tid;                  // coalesced dict reads
            float sim = 0.f, nd = 0.f;
            for (int d = 0; d < DIM; ++d) {
                const float dv = dict[(size_t)d * NCODE + k];
                const float fv = xr[d];                    // broadcast (L1)
                sim = fmaf(fv, dv, sim);                   // BLAS-style FMA chain, d asc
                nd  = __fadd_rn(nd, __fmul_rn(dv, dv));    // np axis-0 reduce
            }
            const float dist = __fsub_rn(__fadd_rn(nf, nd), __fmul_rn(2.f, sim));
            if (dist < bd) { bd = dist; bk = k; }
        }
        red_d[tid] = bd; red_k[tid] = bk;
        __syncthreads();
        for (int s = 128; s > 0; s >>= 1) {
            if (tid < s) {
                const float od = red_d[tid + s]; const int ok = red_k[tid + s];
                if (od < red_d[tid] || (od == red_d[tid] && ok < red_k[tid])) {
                    red_d[tid] = od; red_k[tid] = ok;
                }
            }
            __syncthreads();
        }
        if (tid == 0) row_k1[r] = red_k[0];
        __syncthreads();
    }

    // epilogue: q = 0.5*dictT[kstar]; out = fl(x + fl(q-x)) (np-exact); loss partial
    float lsum = 0.f;
#pragma unroll 2
    for (int i = 0; i < 16; ++i) {
        const int e = i * 1024 + tid * 4;
        const int r = e >> 8, d0 = e & 255;
        const int kk = row_k1[r];
        const float4 dv = *(const float4*)&dictT[(size_t)kk * DIM + d0];
        const float4 xv = *(const float4*)&x[(size_t)row0 * DIM + e];
        float4 qv; qv.x = 0.5f * dv.x; qv.y = 0.5f * dv.y; qv.z = 0.5f * dv.z; qv.w = 0.5f * dv.w;
        float4 ov;
        ov.x = __fadd_rn(xv.x, __fsub_rn(qv.x, xv.x));
        ov.y = __fadd_rn(xv.y, __fsub_rn(qv.y, xv.y));
        ov.z = __fadd_rn(xv.z, __fsub_rn(qv.z, xv.z));
        ov.w = __fadd_rn(xv.w, __fsub_rn(qv.w, xv.w));
        const float e0 = __fsub_rn(xv.x, qv.x), e1 = __fsub_rn(xv.y, qv.y);
        const float e2 = __fsub_rn(xv.z, qv.z), e3 = __fsub_rn(xv.w, qv.w);
        lsum += e0 * e0 + e1 * e1 + e2 * e2 + e3 * e3;
        *(float4*)&out[(size_t)row0 * DIM + e] = ov;
    }

#pragma unroll
    for (int sft = 32; sft > 0; sft >>= 1) lsum += __shfl_down(lsum, sft, 64);
    if ((tid & 63) == 0) wred[tid >> 6] = lsum;
    __syncthreads();
    if (tid == 0)
        block_sums[blockIdx.x] = (double)((wred[0] + wred[1]) + (wred[2] + wred[3]));
}

// ---------- loss finalize ----------

__global__ void k_finalize(const double* __restrict__ block_sums, float* __restrict__ out_loss) {
    __shared__ double w[16];
    const int t = threadIdx.x;                  // 1024 threads
    double v = block_sums[t];
#pragma unroll
    for (int sft = 32; sft > 0; sft >>= 1) v += __shfl_down(v, sft, 64);
    if ((t & 63) == 0) w[t >> 6] = v;
    __syncthreads();
    if (t == 0) {
        double tot = 0.0;
        for (int i = 0; i < 16; ++i) tot += w[i];
        out_loss[0] = (float)(1.25 * tot / (double)(NROWS * DIM));
    }
}

// ---------- launch ----------

extern "C" void kernel_launch(void* const* d_in, const int* in_sizes, int n_in,
                              void* d_out, int out_size, void* d_ws, size_t ws_size,
                              hipStream_t stream) {
    (void)in_sizes; (void)n_in; (void)out_size; (void)ws_size;
    const float* x    = (const float*)d_in[0];
    const float* dict = (const float*)d_in[1];
    float* out = (float*)d_out;

    char* ws = (char*)d_ws;
    float*          dictT      = (float*)ws;                          // 1 MB
    float*          dictnorm   = (float*)(ws + 1048576);              // 4 KB
    double*         block_sums = (double*)(ws + 1048576 + 4096);      // 8 KB
    unsigned short* packB      = (unsigned short*)(ws + 1048576 + 4096 + 8192); // 512 KB

    k_prep<<<256, 256, 0, stream>>>(dict, dictT, dictnorm, packB);
    k_vq<<<NBLK, 256, 0, stream>>>(x, dict, dictT, dictnorm, packB, out, block_sums);
    k_finalize<<<1, 1024, 0, stream>>>(block_sums, out + (size_t)NROWS * DIM);
}

// Round 7
// 335.026 us; speedup vs baseline: 1.1724x; 1.1724x over previous
//
#include <hip/hip_runtime.h>

// VQBlock: x[16,64,64,256] fp32, dict[256,1024] fp32.
// out = concat(q_st flat [16777216], loss [1]) fp32.
//
// Round 9 = r7 (238us, proven) + T3-minimum 2-phase pipeline:
//  - r7+r8 joint lesson: LDS staging beats direct-L2 B reads (238 vs 323),
//    but r7 issues staging loads immediately before the vmcnt(0) drain ->
//    full load latency exposed serially每chunk. Fix: issue chunk cc+1's
//    global_load_lds BEFORE computing chunk cc (dbuf LDS); the loop-bottom
//    __syncthreads drain then finds loads already landed (latency hidden
//    under ds_read+MFMA+select). Guide §5.5 T3-minimum recipe.
//  - Chunk shrunk 64->32 codes so dbuf = 2x16KB; total LDS ~35.6KB keeps
//    4 blocks/CU = 16 waves/CU (r2's 64KB dbuf halved occupancy -> 327us).
//  - global_load_lds staging (no VGPR round-trip, no ds_write phase);
//    LDS dest tid-linear (wave-uniform base + lane*16 -- m104 rule).
//  - k_prep flipped to coalesced dict reads + scattered writes (old pack
//    read was column-strided, ~16x amplified).
//  - Packed-u32 branchless top-2 (absmax 0.0 r5-r8): EPS_TIE 6e-3,
//    dictnorm +8 bias; ambiguous rows -> unchanged np-fp32-faithful rescan.
//  - q_st written as fl(x + fl(q-x)) to match np exactly.

#define NROWS   65536
#define DIM     256
#define NCODE   1024
#define RPB     64                  // rows per block = 4 waves x 16 rows
#define NBLK    (NROWS / RPB)       // 1024
#define NCHUNK  32                  // 32 codes per chunk
#define EPS_TIE 6e-3f

typedef _Float16 half8 __attribute__((ext_vector_type(8)));
typedef float    f32x4 __attribute__((ext_vector_type(4)));

// ---------- merged prep kernel ----------
// One coalesced read of dict[e]; scatter-write transpose + f16 MFMA-B pack.
// pack position for dict element (d, k):
//   cc=k>>5, t=(k>>4)&1, l15=k&15, kk=d>>5, q=(d>>3)&3, j=d&7
//   o = cc*8192 + (kk*2+t)*512 + q*128 + l15*8 + j
// (= the LDS image: fragment (kk,t) is 1KB lane-ordered [q][l15][j])
__global__ void k_prep(const float* __restrict__ dict, float* __restrict__ dictT,
                       float* __restrict__ dictnorm, unsigned short* __restrict__ packB) {
    int gid = blockIdx.x * 256 + threadIdx.x;          // grid 256 x 256
#pragma unroll
    for (int ii = 0; ii < 4; ++ii) {
        int e = ii * 65536 + gid;                      // coalesced read
        const float v = dict[e];
        const int d = e >> 10, k = e & 1023;
        dictT[k * DIM + d] = v;                        // scatter 4B write
        _Float16 h = (_Float16)v;                      // RTN cvt
        const int o = (k >> 5) * 8192 + ((d >> 5) * 2 + ((k >> 4) & 1)) * 512
                    + ((d >> 3) & 3) * 128 + (k & 15) * 8 + (d & 7);
        packB[o] = *(unsigned short*)&h;               // scatter 2B write
    }
    if (blockIdx.x < 4) {
        int k = blockIdx.x * 256 + threadIdx.x;        // coalesced column sums
        float s = 0.f;
#pragma unroll 8
        for (int d = 0; d < DIM; ++d) {
            float v = dict[d * NCODE + k];
            s = fmaf(v, v, s);
        }
        dictnorm[k] = s + 8.0f;    // bias for packed-selection positivity; cancels in gaps
    }
}

// np pairwise sum of squares of 128 contiguous elements
__device__ __forceinline__ float np_pairwise_sq_128(const float* a, int stride) {
    float r[8];
#pragma unroll
    for (int j = 0; j < 8; ++j) {
        float v = a[j * stride];
        r[j] = __fmul_rn(v, v);
    }
    for (int i = 8; i < 128; i += 8) {
#pragma unroll
        for (int j = 0; j < 8; ++j) {
            float v = a[(i + j) * stride];
            r[j] = __fadd_rn(r[j], __fmul_rn(v, v));
        }
    }
    return __fadd_rn(__fadd_rn(__fadd_rn(r[0], r[1]), __fadd_rn(r[2], r[3])),
                     __fadd_rn(__fadd_rn(r[4], r[5]), __fadd_rn(r[6], r[7])));
}

// ---------- main kernel ----------

// Stage chunk cc (16KB) into bstage[buf] via 4 x global_load_lds, tid-linear.
#define STAGE(buf, cc) do {                                                            \
    const unsigned short* _s = packB + (size_t)(cc) * 8192 + tid * 8;                  \
    unsigned short* _d = &bstage[buf][tid * 8];                                        \
    _Pragma("unroll")                                                                  \
    for (int _p = 0; _p < 4; ++_p)                                                     \
        __builtin_amdgcn_global_load_lds(                                              \
            (const __attribute__((address_space(1))) unsigned int*)(_s + _p * 2048),   \
            (__attribute__((address_space(3))) unsigned int*)(_d + _p * 2048),         \
            16, 0, 0);                                                                 \
} while (0)

__global__ __launch_bounds__(256, 4) void k_vq(
    const float* __restrict__ x, const float* __restrict__ dict,
    const float* __restrict__ dictT, const float* __restrict__ dictnorm,
    const unsigned short* __restrict__ packB,
    float* __restrict__ out, double* __restrict__ block_sums)
{
    __shared__ __align__(16) unsigned short bstage[2][8192];  // 2 x 16 KB dbuf
    __shared__ float row_gap[RPB];
    __shared__ int   row_k1[RPB];
    __shared__ float red_d[256];
    __shared__ int   red_k[256];
    __shared__ float wred[4];
    __shared__ int   amb_list[RPB];
    __shared__ int   amb_cnt;

    const int tid  = threadIdx.x;
    const int ln   = tid & 63, wv = tid >> 6;
    const int l15  = ln & 15, q = ln >> 4;
    const int row0 = blockIdx.x * RPB;

    // issue chunk-0 staging immediately; it flies while we build A fragments
    STAGE(0, 0);
    if (tid == 0) amb_cnt = 0;

    // A fragments (register-resident, reused over all 32 chunks):
    // lane provides A row m=l15 (x row row0 + wv*16 + l15), k = kk*32 + q*8 + j
    half8 afrag[8];
    {
        const float* ar = x + (size_t)(row0 + wv * 16 + l15) * DIM + q * 8;
#pragma unroll
        for (int kk = 0; kk < 8; ++kk) {
            const float4 p0 = *(const float4*)(ar + kk * 32);
            const float4 p1 = *(const float4*)(ar + kk * 32 + 4);
            half8 h;
            h[0] = (_Float16)p0.x; h[1] = (_Float16)p0.y; h[2] = (_Float16)p0.z; h[3] = (_Float16)p0.w;
            h[4] = (_Float16)p1.x; h[5] = (_Float16)p1.y; h[6] = (_Float16)p1.z; h[7] = (_Float16)p1.w;
            afrag[kk] = h;
        }
    }

    // packed top-2 per lane for its 4 C-rows (local rows q*4+i)
    unsigned p1v[4], p2v[4];
#pragma unroll
    for (int i = 0; i < 4; ++i) { p1v[i] = 0xFFFFFFFFu; p2v[i] = 0xFFFFFFFFu; }

    __syncthreads();                                   // chunk-0 staged

    for (int cc = 0; cc < NCHUNK; ++cc) {
        const int cur = cc & 1;
        if (cc < NCHUNK - 1) STAGE(cur ^ 1, cc + 1);   // prefetch next chunk NOW;
                                                       // it lands during compute below
        const int c0 = cc * 32;
        float dn[2];
#pragma unroll
        for (int t = 0; t < 2; ++t) dn[t] = dictnorm[c0 + t * 16 + l15];   // ||d||^2 + 8

        const f32x4 zero = {0.f, 0.f, 0.f, 0.f};
        f32x4 acc[2];
        acc[0] = zero; acc[1] = zero;

#pragma unroll
        for (int kk = 0; kk < 8; ++kk) {
#pragma unroll
            for (int t = 0; t < 2; ++t) {
                // contiguous 1KB/wave ds_read_b128: lane (q,l15) at
                // (kk*2+t)*512 + q*128 + l15*8 shorts -> conflict-free
                const half8 b = *(const half8*)&bstage[cur][(kk * 2 + t) * 512 + q * 128 + l15 * 8];
                acc[t] = __builtin_amdgcn_mfma_f32_16x16x32_f16(afrag[kk], b, acc[t], 0, 0, 0);
            }
        }

        // packed top-2 update: branchless, index-ascending tiebreak
#pragma unroll
        for (int t = 0; t < 2; ++t) {
            const unsigned kbase = (unsigned)(c0 + t * 16 + l15);
#pragma unroll
            for (int i = 0; i < 4; ++i) {
                const float s = fmaf(-2.f, acc[t][i], dn[t]);      // in (1.8, 14.6)
                const unsigned pk = (__float_as_uint(s) & 0xFFFFFC00u) | kbase;
                const unsigned mx = p1v[i] > pk ? p1v[i] : pk;
                p2v[i] = p2v[i] < mx ? p2v[i] : mx;
                p1v[i] = p1v[i] < pk ? p1v[i] : pk;
            }
        }
        // drain (loads for cc+1 have had the whole compute phase to land) + sync
        __syncthreads();
    }

    // top-2 merge across the 16 lanes sharing quad q (they hold the same 4 rows)
#pragma unroll
    for (int i = 0; i < 4; ++i) {
        unsigned a1 = p1v[i], a2 = p2v[i];
#pragma unroll
        for (int m = 1; m < 16; m <<= 1) {
            const unsigned o1 = __shfl_xor(a1, m);
            const unsigned o2 = __shfl_xor(a2, m);
            const unsigned mx = a1 > o1 ? a1 : o1;
            a1 = a1 < o1 ? a1 : o1;
            const unsigned mn2 = a2 < o2 ? a2 : o2;
            a2 = mx < mn2 ? mx : mn2;
        }
        if (l15 == 0) {
            const int r = wv * 16 + q * 4 + i;
            row_k1[r]  = (int)(a1 & 1023u);
            row_gap[r] = __uint_as_float(a2 & 0xFFFFFC00u) - __uint_as_float(a1 & 0xFFFFFC00u);
        }
    }
    __syncthreads();

    if (tid < RPB && row_gap[tid] < EPS_TIE) {
        int p = atomicAdd(&amb_cnt, 1);
        amb_list[p] = tid;
    }
    __syncthreads();
    const int namb = amb_cnt;

    // np-fp32-faithful full rescan of ambiguous rows (proven; unchanged)
    for (int a = 0; a < namb; ++a) {
        const int r = amb_list[a];
        const float* xr = x + (size_t)(row0 + r) * DIM;
        const float nf = __fadd_rn(np_pairwise_sq_128(xr, 1), np_pairwise_sq_128(xr + 128, 1));
        float bd = 3.4e38f; int bk = 0x7fffffff;
#pragma unroll
        for (int i = 0; i < 4; ++i) {
            const int k = i * 256 + tid;                  // coalesced dict reads
            float sim = 0.f, nd = 0.f;
            for (int d = 0; d < DIM; ++d) {
                const float dv = dict[(size_t)d * NCODE + k];
                const float fv = xr[d];                    // broadcast (L1)
                sim = fmaf(fv, dv, sim);                   // BLAS-style FMA chain, d asc
                nd  = __fadd_rn(nd, __fmul_rn(dv, dv));    // np axis-0 reduce
            }
            const float dist = __fsub_rn(__fadd_rn(nf, nd), __fmul_rn(2.f, sim));
            if (dist < bd) { bd = dist; bk = k; }
        }
        red_d[tid] = bd; red_k[tid] = bk;
        __syncthreads();
        for (int s = 128; s > 0; s >>= 1) {
            if (tid < s) {
                const float od = red_d[tid + s]; const int ok = red_k[tid + s];
                if (od < red_d[tid] || (od == red_d[tid] && ok < red_k[tid])) {
                    red_d[tid] = od; red_k[tid] = ok;
                }
            }
            __syncthreads();
        }
        if (tid == 0) row_k1[r] = red_k[0];
        __syncthreads();
    }

    // epilogue: q = 0.5*dictT[kstar]; out = fl(x + fl(q-x)) (np-exact); loss partial
    float lsum = 0.f;
#pragma unroll 2
    for (int i = 0; i < 16; ++i) {
        const int e = i * 1024 + tid * 4;
        const int r = e >> 8, d0 = e & 255;
        const int kk = row_k1[r];
        const float4 dv = *(const float4*)&dictT[(size_t)kk * DIM + d0];
        const float4 xv = *(const float4*)&x[(size_t)row0 * DIM + e];
        float4 qv; qv.x = 0.5f * dv.x; qv.y = 0.5f * dv.y; qv.z = 0.5f * dv.z; qv.w = 0.5f * dv.w;
        float4 ov;
        ov.x = __fadd_rn(xv.x, __fsub_rn(qv.x, xv.x));
        ov.y = __fadd_rn(xv.y, __fsub_rn(qv.y, xv.y));
        ov.z = __fadd_rn(xv.z, __fsub_rn(qv.z, xv.z));
        ov.w = __fadd_rn(xv.w, __fsub_rn(qv.w, xv.w));
        const float e0 = __fsub_rn(xv.x, qv.x), e1 = __fsub_rn(xv.y, qv.y);
        const float e2 = __fsub_rn(xv.z, qv.z), e3 = __fsub_rn(xv.w, qv.w);
        lsum += e0 * e0 + e1 * e1 + e2 * e2 + e3 * e3;
        *(float4*)&out[(size_t)row0 * DIM + e] = ov;
    }

#pragma unroll
    for (int sft = 32; sft > 0; sft >>= 1) lsum += __shfl_down(lsum, sft, 64);
    if ((tid & 63) == 0) wred[tid >> 6] = lsum;
    __syncthreads();
    if (tid == 0)
        block_sums[blockIdx.x] = (double)((wred[0] + wred[1]) + (wred[2] + wred[3]));
}

// ---------- loss finalize ----------

__global__ void k_finalize(const double* __restrict__ block_sums, float* __restrict__ out_loss) {
    __shared__ double w[16];
    const int t = threadIdx.x;                  // 1024 threads
    double v = block_sums[t];
#pragma unroll
    for (int sft = 32; sft > 0; sft >>= 1) v += __shfl_down(v, sft, 64);
    if ((t & 63) == 0) w[t >> 6] = v;
    __syncthreads();
    if (t == 0) {
        double tot = 0.0;
        for (int i = 0; i < 16; ++i) tot += w[i];
        out_loss[0] = (float)(1.25 * tot / (double)(NROWS * DIM));
    }
}

// ---------- launch ----------

extern "C" void kernel_launch(void* const* d_in, const int* in_sizes, int n_in,
                              void* d_out, int out_size, void* d_ws, size_t ws_size,
                              hipStream_t stream) {
    (void)in_sizes; (void)n_in; (void)out_size; (void)ws_size;
    const float* x    = (const float*)d_in[0];
    const float* dict = (const float*)d_in[1];
    float* out = (float*)d_out;

    char* ws = (char*)d_ws;
    float*          dictT      = (float*)ws;                          // 1 MB
    float*          dictnorm   = (float*)(ws + 1048576);              // 4 KB
    double*         block_sums = (double*)(ws + 1048576 + 4096);      // 8 KB
    unsigned short* packB      = (unsigned short*)(ws + 1048576 + 4096 + 8192); // 512 KB

    k_prep<<<256, 256, 0, stream>>>(dict, dictT, dictnorm, packB);
    k_vq<<<NBLK, 256, 0, stream>>>(x, dict, dictT, dictnorm, packB, out, block_sums);
    k_finalize<<<1, 1024, 0, stream>>>(block_sums, out + (size_t)NROWS * DIM);
}